// Round 3
// baseline (292.627 us; speedup 1.0000x reference)
//
#include <hip/hip_runtime.h>
#include <hip/hip_bf16.h>
#include <cstddef>
#include <cstdint>

// Problem constants
#define B   32
#define C   16
#define H   64
#define D   256
#define K   2048
#define T   15
#define PAD 7
#define EPS 1e-5

#define BH      (B*H)       // 2048
#define ROWS    (B*C*H)     // 32768 VQ rows
#define N_PER_CH ((double)(B*H*D)) // 524288
#define NC  16              // candidates per row total (8 per N-half)

typedef __attribute__((ext_vector_type(8))) short bf16x8;
typedef __attribute__((ext_vector_type(4))) float f32x4;

__device__ __forceinline__ void gload_lds16(const void* g, void* l) {
  __builtin_amdgcn_global_load_lds(
      (const __attribute__((address_space(1))) unsigned int*)g,
      (__attribute__((address_space(3))) unsigned int*)l, 16, 0, 0);
}

// ---------------------------------------------------------------------------
// K1: encoder conv (f64) + per-block partial sums for BN stats (deterministic)
// ---------------------------------------------------------------------------
__global__ __launch_bounds__(256) void k1_conv_stats(
    const float* __restrict__ x, const float* __restrict__ w,
    double* __restrict__ partial /* [BH][C][2] */) {
  __shared__ float xs[D + 2*PAD];
  __shared__ float wsm[C*T];
  __shared__ double red[4][C][2];
  const int bh  = blockIdx.x;
  const int tid = threadIdx.x;
  const float* xrow = x + (size_t)bh * D;
  if (tid < C*T) wsm[tid] = w[tid];
  xs[tid + PAD] = xrow[tid];
  if (tid < PAD) { xs[tid] = 0.f; xs[tid + PAD + D] = 0.f; }
  __syncthreads();
  const int d = tid;
#pragma unroll
  for (int c = 0; c < C; c++) {
    double z = 0.0;
#pragma unroll
    for (int t = 0; t < T; t++)
      z = fma((double)wsm[c*T + t], (double)xs[d + t], z);
    double zz = z * z;
#pragma unroll
    for (int off = 32; off; off >>= 1) {
      z  += __shfl_down(z,  off, 64);
      zz += __shfl_down(zz, off, 64);
    }
    if ((tid & 63) == 0) { red[tid >> 6][c][0] = z; red[tid >> 6][c][1] = zz; }
  }
  __syncthreads();
  if (tid < C*2) {
    int c = tid >> 1, j = tid & 1;
    double v = red[0][c][j] + red[1][c][j] + red[2][c][j] + red[3][c][j];
    partial[(size_t)bh * (C*2) + c*2 + j] = v;
  }
}

// ---------------------------------------------------------------------------
// K2: finalize BN per-channel params (deterministic tree)
// ---------------------------------------------------------------------------
__global__ __launch_bounds__(256) void k2_stats_final(
    const double* __restrict__ partial, const float* __restrict__ gamma,
    const float* __restrict__ beta, double* __restrict__ params) {
  __shared__ double rs[256], rq[256];
  const int c = blockIdx.x;
  const int tid = threadIdx.x;
  double s = 0.0, q = 0.0;
  for (int i = tid; i < BH; i += 256) {
    s += partial[(size_t)i * (C*2) + c*2 + 0];
    q += partial[(size_t)i * (C*2) + c*2 + 1];
  }
  rs[tid] = s; rq[tid] = q;
  __syncthreads();
  for (int off = 128; off; off >>= 1) {
    if (tid < off) { rs[tid] += rs[tid + off]; rq[tid] += rq[tid + off]; }
    __syncthreads();
  }
  if (tid == 0) {
    double m = rs[0] / N_PER_CH;
    double v = rq[0] / N_PER_CH - m * m;
    double a = (double)gamma[c] / sqrt(v + EPS);
    double b = (double)beta[c] - a * m;
    params[c*4+0] = m; params[c*4+1] = v; params[c*4+2] = a; params[c*4+3] = b;
  }
}

// ---------------------------------------------------------------------------
// K6: ||e_k||^2 in f64 (+f32 copy) + bf16 copy of emb. grid=K, 64 thr
// ---------------------------------------------------------------------------
__global__ __launch_bounds__(64) void k6_enorm(
    const float* __restrict__ emb, double* __restrict__ enorm,
    float* __restrict__ enormf, __hip_bfloat16* __restrict__ embB) {
  const int k = blockIdx.x;
  const int tid = threadIdx.x;
  const float* er = emb + (size_t)k * D;
  double s = 0.0;
  for (int i = tid; i < D; i += 64) {
    float e = er[i];
    embB[(size_t)k * D + i] = __float2bfloat16(e);
    double ed = (double)e;
    s = fma(ed, ed, s);
  }
#pragma unroll
  for (int off = 32; off; off >>= 1) s += __shfl_down(s, off, 64);
  if (tid == 0) { enorm[k] = s; enormf[k] = (float)s; }
}

// ---------------------------------------------------------------------------
// K3: recompute conv (f64) + affine -> z_e (f32) + z_e bf16 copy
// ---------------------------------------------------------------------------
__global__ __launch_bounds__(256) void k3_ze(
    const float* __restrict__ x, const float* __restrict__ w,
    const double* __restrict__ params, float* __restrict__ zE,
    __hip_bfloat16* __restrict__ zEb) {
  __shared__ float xs[D + 2*PAD];
  __shared__ float wsm[C*T];
  const int bh  = blockIdx.x;
  const int b = bh >> 6, h = bh & 63;
  const int tid = threadIdx.x;
  const float* xrow = x + (size_t)bh * D;
  if (tid < C*T) wsm[tid] = w[tid];
  xs[tid + PAD] = xrow[tid];
  if (tid < PAD) { xs[tid] = 0.f; xs[tid + PAD + D] = 0.f; }
  __syncthreads();
  const int d = tid;
#pragma unroll
  for (int c = 0; c < C; c++) {
    double z = 0.0;
#pragma unroll
    for (int t = 0; t < T; t++)
      z = fma((double)wsm[c*T + t], (double)xs[d + t], z);
    double ze = fma(params[c*4+2], z, params[c*4+3]);
    float zf = (float)ze;
    size_t idx = (((size_t)b*C + c)*H + h)*D + d;
    zE[idx] = zf;
    zEb[idx] = __float2bfloat16(zf);
  }
}

// ---------------------------------------------------------------------------
// K4: MFMA phase-A, fragment-order LDS (conflict-free b128 reads).
// Block = 128 rows x 1024 cols (N-half). 4 waves (2x2), wave tile 64x64.
// A slab resident (64KB, frag layout), B 2-slot ring (16KB), counted vmcnt.
// u32-packed (crit|col) top-2 trackers -> per-row top-8 -> cand.
// ---------------------------------------------------------------------------
__global__ __launch_bounds__(256) void k4_mfma(
    const __hip_bfloat16* __restrict__ zEb, const __hip_bfloat16* __restrict__ embB,
    const float* __restrict__ enormf, int* __restrict__ cand /*[ROWS][NC]*/) {
  // frag = 64 lanes x 8 bf16 (16B/lane). A: [kk*8+mf][512], B: [slot][nf][512]
  __shared__ __attribute__((aligned(16))) __hip_bfloat16 Ash[64][512];   // 64 KB
  __shared__ __attribute__((aligned(16))) __hip_bfloat16 Bsh[2][8][512]; // 16 KB

  const int tid  = threadIdx.x;
  const int w    = tid >> 6, lane = tid & 63;
  const int wr   = w >> 1,   wc   = w & 1;
  const int l15  = lane & 15, l4  = lane >> 4;
  const int mblk = blockIdx.x >> 1, nhalf = blockIdx.x & 1;
  const int row0 = mblk * 128;
  const int n0   = nhalf * 1024;

  // ---- prologue: A slab (64 frags) + B step 0 ----
#pragma unroll
  for (int i = 0; i < 16; i++) {
    int f = w*16 + i;
    int kk = f >> 3, mf = f & 7;
    gload_lds16(zEb + (((size_t)(row0 + mf*16 + l15)) << 8) + kk*32 + l4*8,
                &Ash[kk*8 + mf][0]);
  }
  auto stageB = [&](int t) {
    const int slot = t & 1, nt = t >> 3, kk = t & 7;
#pragma unroll
    for (int j = 0; j < 2; j++) {
      int nf = w*2 + j;
      gload_lds16(embB + (((size_t)(n0 + nt*128 + nf*16 + l15)) << 8) + kk*32 + l4*8,
                  &Bsh[slot][nf][0]);
    }
  };
  stageB(0);
  asm volatile("s_waitcnt vmcnt(0) lgkmcnt(0)" ::: "memory");
  __builtin_amdgcn_sched_barrier(0);
  __builtin_amdgcn_s_barrier();

  // trackers: 16 row-slots (m*4+reg), top-2 as packed u32 keys (crit<<11 | col)
  unsigned t0[16], t1[16];
#pragma unroll
  for (int s = 0; s < 16; s++) { t0[s] = 0xFFFFFFFFu; t1[s] = 0xFFFFFFFFu; }

  f32x4 acc[4][4];
  for (int t = 0; t < 64; t++) {
    const int kk = t & 7;
    if (kk == 0) {
#pragma unroll
      for (int m = 0; m < 4; m++)
#pragma unroll
        for (int n = 0; n < 4; n++) acc[m][n] = (f32x4){0.f, 0.f, 0.f, 0.f};
    }
    if (t) __builtin_amdgcn_s_barrier();       // barrier_A: prev-step reads done
    if (t < 63) stageB(t + 1);
    if (t < 63) asm volatile("s_waitcnt vmcnt(2)" ::: "memory");
    else        asm volatile("s_waitcnt vmcnt(0)" ::: "memory");
    __builtin_amdgcn_sched_barrier(0);
    __builtin_amdgcn_s_barrier();              // barrier_B: stage(t) visible to all

    bf16x8 af[4], bfr[4];
#pragma unroll
    for (int m = 0; m < 4; m++)
      af[m] = *(const bf16x8*)&Ash[kk*8 + wr*4 + m][lane*8];
#pragma unroll
    for (int n = 0; n < 4; n++)
      bfr[n] = *(const bf16x8*)&Bsh[t & 1][wc*4 + n][lane*8];
#pragma unroll
    for (int m = 0; m < 4; m++)
#pragma unroll
      for (int n = 0; n < 4; n++)
        acc[m][n] = __builtin_amdgcn_mfma_f32_16x16x32_bf16(af[m], bfr[n], acc[m][n], 0, 0, 0);

    if (kk == 7) {                              // per-nt criterion epilogue
      const int nt = t >> 3;
#pragma unroll
      for (int n = 0; n < 4; n++) {
        const int col = n0 + nt*128 + (wc*4 + n)*16 + l15;
        const float en = enormf[col];
#pragma unroll
        for (int m = 0; m < 4; m++) {
#pragma unroll
          for (int r = 0; r < 4; r++) {
            const float cv = fmaf(-2.f, acc[m][n][r], en);
            unsigned u = __float_as_uint(cv);
            unsigned key = u ^ ((unsigned)((int)u >> 31) | 0x80000000u);
            key = (key & ~2047u) | (unsigned)col;
            const int s = m*4 + r;
            unsigned mx = key > t0[s] ? key : t0[s];
            t0[s] = key < t0[s] ? key : t0[s];
            t1[s] = mx < t1[s] ? mx : t1[s];
          }
        }
      }
    }
  }

  // ---- merge 32 trackers x top-2 -> top-8 per row ----
  __syncthreads();
  unsigned* KeyM = (unsigned*)&Ash[0][0];      // [128 rows][64 entries] = 32 KB
  const int tk = wc*16 + l15;
#pragma unroll
  for (int s = 0; s < 16; s++) {
    const int r = wr*64 + (s >> 2)*16 + l4*4 + (s & 3);
    KeyM[r*64 + tk*2 + 0] = t0[s];
    KeyM[r*64 + tk*2 + 1] = t1[s];
  }
  __syncthreads();
  if (tid < 128) {
    unsigned bk[8];
#pragma unroll
    for (int j = 0; j < 8; j++) bk[j] = 0xFFFFFFFFu;
    for (int e = 0; e < 64; e++) {
      unsigned v = KeyM[tid*64 + e];
      if (v < bk[7]) {
        int j = 7;
        while (j > 0 && v < bk[j-1]) { bk[j] = bk[j-1]; j--; }
        bk[j] = v;
      }
    }
    int* cr = cand + ((size_t)(row0 + tid)) * NC + nhalf*8;
#pragma unroll
    for (int j = 0; j < 8; j++) cr[j] = (int)(bk[j] & 2047u);
  }
}

// ---------------------------------------------------------------------------
// K5: f64 exact rescore. Block per (b,h): 16 channels share one f64 conv.
// 256 thr: conv d-parallel; rescore 16 rows x NC cands (wave per 4 rows).
// ---------------------------------------------------------------------------
__global__ __launch_bounds__(256) void k5_rescore(
    const float* __restrict__ x, const float* __restrict__ w,
    const double* __restrict__ params, const float* __restrict__ emb,
    const double* __restrict__ enorm, const int* __restrict__ cand,
    float* __restrict__ zq) {
  __shared__ float xs[D + 2*PAD];
  __shared__ float wsm[C*T];
  __shared__ double pa[C], pb[C];
  __shared__ double ze[C][D];                  // 32 KB
  const int bh = blockIdx.x;
  const int b = bh >> 6, h = bh & 63;
  const int tid = threadIdx.x;
  const float* xrow = x + (size_t)bh * D;
  if (tid < C*T) wsm[tid] = w[tid];
  if (tid >= C*T && tid < C*T + C) { int c = tid - C*T; pa[c] = params[c*4+2]; pb[c] = params[c*4+3]; }
  xs[tid + PAD] = xrow[tid];
  if (tid < PAD) { xs[tid] = 0.f; xs[D + PAD + tid] = 0.f; }
  __syncthreads();
  const int d = tid;
#pragma unroll
  for (int c = 0; c < C; c++) {
    double z = 0.0;
#pragma unroll
    for (int t = 0; t < T; t++) z = fma((double)wsm[c*T + t], (double)xs[d + t], z);
    ze[c][d] = fma(pa[c], z, pb[c]);
  }
  __syncthreads();
  const int wv = tid >> 6, lane = tid & 63;
#pragma unroll
  for (int i = 0; i < 4; i++) {
    const int c = wv*4 + i;
    const size_t rid = ((size_t)b*C + c)*H + h;
    const int* cr = cand + rid * NC;
    double bestv = 1e300; int bestk = K;
    const double* zr = ze[c];
    for (int j = 0; j < NC; j++) {
      int k = cr[j];
      const float4 ev = *(const float4*)(emb + ((size_t)k << 8) + lane*4);
      double dot = fma((double)ev.x, zr[lane*4+0],
                   fma((double)ev.y, zr[lane*4+1],
                   fma((double)ev.z, zr[lane*4+2],
                       (double)ev.w * zr[lane*4+3])));
#pragma unroll
      for (int off = 32; off; off >>= 1) dot += __shfl_down(dot, off, 64);
      dot = __shfl(dot, 0, 64);
      double cv = enorm[k] - 2.0 * dot;
      if (cv < bestv || (cv == bestv && k < bestk)) { bestv = cv; bestk = k; }
    }
    const float4 ev = *(const float4*)(emb + ((size_t)bestk << 8) + lane*4);
    *(float4*)(zq + (rid << 8) + lane*4) = ev;
  }
}

// ---------------------------------------------------------------------------
// K7: decoder (transposed conv == conv with flipped kernel) + tanh, f32
// ---------------------------------------------------------------------------
__global__ __launch_bounds__(256) void k7_decode(
    const float* __restrict__ zq, const float* __restrict__ wdec,
    float* __restrict__ xt) {
  __shared__ float zs[C][D + 2*PAD];
  __shared__ float wt[C*T];
  const int bh = blockIdx.x;
  const int b = bh >> 6, h = bh & 63;
  const int tid = threadIdx.x;
  if (tid < C*T) { int c = tid / T, t = tid % T; wt[c*T + t] = wdec[c*T + (T-1-t)]; }
  for (int i = tid; i < C*D; i += 256) {
    int c = i >> 8, d = i & 255;
    zs[c][d + PAD] = zq[((size_t)(b*C*H + c*H + h)) * D + d];
  }
  if (tid < C*2*PAD) {
    int c = tid / (2*PAD), j = tid % (2*PAD);
    zs[c][j < PAD ? j : (D + PAD + (j - PAD))] = 0.f;
  }
  __syncthreads();
  const int d = tid;
  float p = 0.f;
#pragma unroll
  for (int c = 0; c < C; c++)
#pragma unroll
    for (int t = 0; t < T; t++)
      p = fmaf(wt[c*T + t], zs[c][d + t], p);
  xt[(size_t)bh * D + d] = tanhf(p);
}

// ---------------------------------------------------------------------------
extern "C" void kernel_launch(void* const* d_in, const int* in_sizes, int n_in,
                              void* d_out, int out_size, void* d_ws, size_t ws_size,
                              hipStream_t stream) {
  const float* x     = (const float*)d_in[0];
  const float* w_enc = (const float*)d_in[1];
  const float* gamma = (const float*)d_in[2];
  const float* beta  = (const float*)d_in[3];
  const float* emb   = (const float*)d_in[4];
  const float* w_dec = (const float*)d_in[5];

  float* out = (float*)d_out;
  float* xt = out;                                    // 524288
  float* zE = out + (size_t)B*H*D;                    // 8388608
  float* zq = out + (size_t)B*H*D + (size_t)B*C*H*D;  // 8388608

  char* ws = (char*)d_ws;
  double* partial = (double*)(ws);                       // 524288 B
  double* params  = (double*)(ws + 524288);              // 512 B
  double* enorm   = (double*)(ws + 524800);              // 16384 B
  float*  enormf  = (float*) (ws + 541184);              // 8192 B
  int*    cand    = (int*)   (ws + 549376);              // 32768*16*4 = 2 MiB
  __hip_bfloat16* zEb  = (__hip_bfloat16*)(ws + 2646528);   // 16 MiB
  __hip_bfloat16* embB = (__hip_bfloat16*)(ws + 19423744);  // 1 MiB

  k1_conv_stats<<<BH, 256, 0, stream>>>(x, w_enc, partial);
  k2_stats_final<<<C, 256, 0, stream>>>(partial, gamma, beta, params);
  k6_enorm<<<K, 64, 0, stream>>>(emb, enorm, enormf, embB);
  k3_ze<<<BH, 256, 0, stream>>>(x, w_enc, params, zE, zEb);
  k4_mfma<<<512, 256, 0, stream>>>(zEb, embB, enormf, cand);
  k5_rescore<<<BH, 256, 0, stream>>>(x, w_enc, params, emb, enorm, cand, zq);
  k7_decode<<<BH, 256, 0, stream>>>(zq, w_dec, xt);
}

// Round 4
// 233.024 us; speedup vs baseline: 1.2558x; 1.2558x over previous
//
#include <hip/hip_runtime.h>
#include <hip/hip_bf16.h>
#include <cstddef>
#include <cstdint>

// Problem constants
#define B   32
#define C   16
#define H   64
#define D   256
#define K   2048
#define T   15
#define PAD 7
#define EPS 1e-5

#define BH      (B*H)       // 2048
#define ROWS    (B*C*H)     // 32768 VQ rows
#define N_PER_CH ((double)(B*H*D)) // 524288
#define NC  16              // candidates per row total (8 per N-half)

typedef __attribute__((ext_vector_type(8))) short bf16x8;
typedef __attribute__((ext_vector_type(4))) float f32x4;

__device__ __forceinline__ void gload_lds16(const void* g, void* l) {
  __builtin_amdgcn_global_load_lds(
      (const __attribute__((address_space(1))) unsigned int*)g,
      (__attribute__((address_space(3))) unsigned int*)l, 16, 0, 0);
}

// ---------------------------------------------------------------------------
// K1: encoder conv (f64) + per-block partial sums for BN stats (deterministic)
// ---------------------------------------------------------------------------
__global__ __launch_bounds__(256) void k1_conv_stats(
    const float* __restrict__ x, const float* __restrict__ w,
    double* __restrict__ partial /* [BH][C][2] */) {
  __shared__ float xs[D + 2*PAD];
  __shared__ float wsm[C*T];
  __shared__ double red[4][C][2];
  const int bh  = blockIdx.x;
  const int tid = threadIdx.x;
  const float* xrow = x + (size_t)bh * D;
  if (tid < C*T) wsm[tid] = w[tid];
  xs[tid + PAD] = xrow[tid];
  if (tid < PAD) { xs[tid] = 0.f; xs[tid + PAD + D] = 0.f; }
  __syncthreads();
  const int d = tid;
#pragma unroll
  for (int c = 0; c < C; c++) {
    double z = 0.0;
#pragma unroll
    for (int t = 0; t < T; t++)
      z = fma((double)wsm[c*T + t], (double)xs[d + t], z);
    double zz = z * z;
#pragma unroll
    for (int off = 32; off; off >>= 1) {
      z  += __shfl_down(z,  off, 64);
      zz += __shfl_down(zz, off, 64);
    }
    if ((tid & 63) == 0) { red[tid >> 6][c][0] = z; red[tid >> 6][c][1] = zz; }
  }
  __syncthreads();
  if (tid < C*2) {
    int c = tid >> 1, j = tid & 1;
    double v = red[0][c][j] + red[1][c][j] + red[2][c][j] + red[3][c][j];
    partial[(size_t)bh * (C*2) + c*2 + j] = v;
  }
}

// ---------------------------------------------------------------------------
// K2: finalize BN per-channel params (deterministic tree)
// ---------------------------------------------------------------------------
__global__ __launch_bounds__(256) void k2_stats_final(
    const double* __restrict__ partial, const float* __restrict__ gamma,
    const float* __restrict__ beta, double* __restrict__ params) {
  __shared__ double rs[256], rq[256];
  const int c = blockIdx.x;
  const int tid = threadIdx.x;
  double s = 0.0, q = 0.0;
  for (int i = tid; i < BH; i += 256) {
    s += partial[(size_t)i * (C*2) + c*2 + 0];
    q += partial[(size_t)i * (C*2) + c*2 + 1];
  }
  rs[tid] = s; rq[tid] = q;
  __syncthreads();
  for (int off = 128; off; off >>= 1) {
    if (tid < off) { rs[tid] += rs[tid + off]; rq[tid] += rq[tid + off]; }
    __syncthreads();
  }
  if (tid == 0) {
    double m = rs[0] / N_PER_CH;
    double v = rq[0] / N_PER_CH - m * m;
    double a = (double)gamma[c] / sqrt(v + EPS);
    double b = (double)beta[c] - a * m;
    params[c*4+0] = m; params[c*4+1] = v; params[c*4+2] = a; params[c*4+3] = b;
  }
}

// ---------------------------------------------------------------------------
// K6: ||e_k||^2 in f64 (+f32 copy) + bf16 copy of emb. grid=K, 64 thr
// ---------------------------------------------------------------------------
__global__ __launch_bounds__(64) void k6_enorm(
    const float* __restrict__ emb, double* __restrict__ enorm,
    float* __restrict__ enormf, __hip_bfloat16* __restrict__ embB) {
  const int k = blockIdx.x;
  const int tid = threadIdx.x;
  const float* er = emb + (size_t)k * D;
  double s = 0.0;
  for (int i = tid; i < D; i += 64) {
    float e = er[i];
    embB[(size_t)k * D + i] = __float2bfloat16(e);
    double ed = (double)e;
    s = fma(ed, ed, s);
  }
#pragma unroll
  for (int off = 32; off; off >>= 1) s += __shfl_down(s, off, 64);
  if (tid == 0) { enorm[k] = s; enormf[k] = (float)s; }
}

// ---------------------------------------------------------------------------
// K3: recompute conv (f64) + affine -> z_e (f32) + z_e bf16 copy
// ---------------------------------------------------------------------------
__global__ __launch_bounds__(256) void k3_ze(
    const float* __restrict__ x, const float* __restrict__ w,
    const double* __restrict__ params, float* __restrict__ zE,
    __hip_bfloat16* __restrict__ zEb) {
  __shared__ float xs[D + 2*PAD];
  __shared__ float wsm[C*T];
  const int bh  = blockIdx.x;
  const int b = bh >> 6, h = bh & 63;
  const int tid = threadIdx.x;
  const float* xrow = x + (size_t)bh * D;
  if (tid < C*T) wsm[tid] = w[tid];
  xs[tid + PAD] = xrow[tid];
  if (tid < PAD) { xs[tid] = 0.f; xs[tid + PAD + D] = 0.f; }
  __syncthreads();
  const int d = tid;
#pragma unroll
  for (int c = 0; c < C; c++) {
    double z = 0.0;
#pragma unroll
    for (int t = 0; t < T; t++)
      z = fma((double)wsm[c*T + t], (double)xs[d + t], z);
    double ze = fma(params[c*4+2], z, params[c*4+3]);
    float zf = (float)ze;
    size_t idx = (((size_t)b*C + c)*H + h)*D + d;
    zE[idx] = zf;
    zEb[idx] = __float2bfloat16(zf);
  }
}

// ---------------------------------------------------------------------------
// K4: MFMA phase-A, fragment-order LDS (conflict-free b128 reads).
// Block = 128 rows x 1024 cols (N-half). 4 waves (2x2), wave tile 64x64.
// A slab resident (64KB, frag layout), B 2-slot ring (16KB), counted vmcnt.
// u32-packed (crit|col) top-2 trackers -> per-row top-8 -> cand.
// ---------------------------------------------------------------------------
__global__ __launch_bounds__(256) void k4_mfma(
    const __hip_bfloat16* __restrict__ zEb, const __hip_bfloat16* __restrict__ embB,
    const float* __restrict__ enormf, int* __restrict__ cand /*[ROWS][NC]*/) {
  // frag = 64 lanes x 8 bf16 (16B/lane). A: [kk*8+mf][512], B: [slot][nf][512]
  __shared__ __attribute__((aligned(16))) __hip_bfloat16 Ash[64][512];   // 64 KB
  __shared__ __attribute__((aligned(16))) __hip_bfloat16 Bsh[2][8][512]; // 16 KB

  const int tid  = threadIdx.x;
  const int w    = tid >> 6, lane = tid & 63;
  const int wr   = w >> 1,   wc   = w & 1;
  const int l15  = lane & 15, l4  = lane >> 4;
  const int mblk = blockIdx.x >> 1, nhalf = blockIdx.x & 1;
  const int row0 = mblk * 128;
  const int n0   = nhalf * 1024;

  // ---- prologue: A slab (64 frags) + B step 0 ----
#pragma unroll
  for (int i = 0; i < 16; i++) {
    int f = w*16 + i;
    int kk = f >> 3, mf = f & 7;
    gload_lds16(zEb + (((size_t)(row0 + mf*16 + l15)) << 8) + kk*32 + l4*8,
                &Ash[kk*8 + mf][0]);
  }
  auto stageB = [&](int t) {
    const int slot = t & 1, nt = t >> 3, kk = t & 7;
#pragma unroll
    for (int j = 0; j < 2; j++) {
      int nf = w*2 + j;
      gload_lds16(embB + (((size_t)(n0 + nt*128 + nf*16 + l15)) << 8) + kk*32 + l4*8,
                  &Bsh[slot][nf][0]);
    }
  };
  stageB(0);
  asm volatile("s_waitcnt vmcnt(0) lgkmcnt(0)" ::: "memory");
  __builtin_amdgcn_sched_barrier(0);
  __builtin_amdgcn_s_barrier();

  // trackers: 16 row-slots (m*4+reg), top-2 as packed u32 keys (crit<<11 | col)
  unsigned t0[16], t1[16];
#pragma unroll
  for (int s = 0; s < 16; s++) { t0[s] = 0xFFFFFFFFu; t1[s] = 0xFFFFFFFFu; }

  f32x4 acc[4][4];
  for (int t = 0; t < 64; t++) {
    const int kk = t & 7;
    if (kk == 0) {
#pragma unroll
      for (int m = 0; m < 4; m++)
#pragma unroll
        for (int n = 0; n < 4; n++) acc[m][n] = (f32x4){0.f, 0.f, 0.f, 0.f};
    }
    if (t) __builtin_amdgcn_s_barrier();       // barrier_A: prev-step reads done
    if (t < 63) stageB(t + 1);
    if (t < 63) asm volatile("s_waitcnt vmcnt(2)" ::: "memory");
    else        asm volatile("s_waitcnt vmcnt(0)" ::: "memory");
    __builtin_amdgcn_sched_barrier(0);
    __builtin_amdgcn_s_barrier();              // barrier_B: stage(t) visible to all

    bf16x8 af[4], bfr[4];
#pragma unroll
    for (int m = 0; m < 4; m++)
      af[m] = *(const bf16x8*)&Ash[kk*8 + wr*4 + m][lane*8];
#pragma unroll
    for (int n = 0; n < 4; n++)
      bfr[n] = *(const bf16x8*)&Bsh[t & 1][wc*4 + n][lane*8];
#pragma unroll
    for (int m = 0; m < 4; m++)
#pragma unroll
      for (int n = 0; n < 4; n++)
        acc[m][n] = __builtin_amdgcn_mfma_f32_16x16x32_bf16(af[m], bfr[n], acc[m][n], 0, 0, 0);

    if (kk == 7) {                              // per-nt criterion epilogue
      const int nt = t >> 3;
#pragma unroll
      for (int n = 0; n < 4; n++) {
        const int col = n0 + nt*128 + (wc*4 + n)*16 + l15;
        const float en = enormf[col];
#pragma unroll
        for (int m = 0; m < 4; m++) {
#pragma unroll
          for (int r = 0; r < 4; r++) {
            const float cv = fmaf(-2.f, acc[m][n][r], en);
            unsigned u = __float_as_uint(cv);
            unsigned key = u ^ ((unsigned)((int)u >> 31) | 0x80000000u);
            key = (key & ~2047u) | (unsigned)col;
            const int s = m*4 + r;
            unsigned mx = key > t0[s] ? key : t0[s];
            t0[s] = key < t0[s] ? key : t0[s];
            t1[s] = mx < t1[s] ? mx : t1[s];
          }
        }
      }
    }
  }

  // ---- merge 32 trackers x top-2 -> top-8 per row ----
  __syncthreads();
  unsigned* KeyM = (unsigned*)&Ash[0][0];      // [128 rows][64 entries] = 32 KB
  const int tk = wc*16 + l15;
#pragma unroll
  for (int s = 0; s < 16; s++) {
    const int r = wr*64 + (s >> 2)*16 + l4*4 + (s & 3);
    KeyM[r*64 + tk*2 + 0] = t0[s];
    KeyM[r*64 + tk*2 + 1] = t1[s];
  }
  __syncthreads();
  if (tid < 128) {
    unsigned bk[8];
#pragma unroll
    for (int j = 0; j < 8; j++) bk[j] = 0xFFFFFFFFu;
    for (int e = 0; e < 64; e++) {
      unsigned v = KeyM[tid*64 + e];
      if (v < bk[7]) {
        int j = 7;
        while (j > 0 && v < bk[j-1]) { bk[j] = bk[j-1]; j--; }
        bk[j] = v;
      }
    }
    int* cr = cand + ((size_t)(row0 + tid)) * NC + nhalf*8;
#pragma unroll
    for (int j = 0; j < 8; j++) cr[j] = (int)(bk[j] & 2047u);
  }
}

// ---------------------------------------------------------------------------
// K5 (fused with decoder): block per (b,h).
//  Phase 1: f64 conv+affine -> ze[C][D] in LDS (d-parallel, matches k1/k3).
//  Phase 2: lane-parallel f64 rescore: wave=channel, 16 cands x 4-lane groups.
//  Phase 3: z_q gather+write + decoder conv + tanh -> x_tilde.
// ---------------------------------------------------------------------------
__global__ __launch_bounds__(256) void k5_fused(
    const float* __restrict__ x, const float* __restrict__ w,
    const double* __restrict__ params, const float* __restrict__ emb,
    const double* __restrict__ enorm, const int* __restrict__ cand,
    const float* __restrict__ wdec,
    float* __restrict__ zq, float* __restrict__ xt) {
  __shared__ float xs[D + 2*PAD];
  __shared__ float wsm[C*T];
  __shared__ float wt[C*T];
  __shared__ double pa[C], pb[C];
  __shared__ double ze[C][D];                  // 32 KB
  __shared__ float zs[C][D + 2*PAD];           // 17.3 KB
  __shared__ int bkS[C];
  const int bh = blockIdx.x;
  const int b = bh >> 6, h = bh & 63;
  const int tid = threadIdx.x;
  const float* xrow = x + (size_t)bh * D;
  if (tid < C*T) {
    wsm[tid] = w[tid];
    int c = tid / T, t = tid % T;
    wt[c*T + t] = wdec[c*T + (T-1-t)];
  }
  if (tid >= C*T && tid < C*T + C) { int c = tid - C*T; pa[c] = params[c*4+2]; pb[c] = params[c*4+3]; }
  xs[tid + PAD] = xrow[tid];
  if (tid < PAD) { xs[tid] = 0.f; xs[D + PAD + tid] = 0.f; }
  __syncthreads();

  // Phase 1: conv (one thread per d, all 16 channels)
  const int d = tid;
#pragma unroll
  for (int c = 0; c < C; c++) {
    double z = 0.0;
#pragma unroll
    for (int t = 0; t < T; t++) z = fma((double)wsm[c*T + t], (double)xs[d + t], z);
    ze[c][d] = fma(pa[c], z, pb[c]);
  }
  __syncthreads();

  // Phase 2: rescore. wave wv handles channels wv*4..wv*4+3.
  const int wv = tid >> 6, lane = tid & 63;
  const int j = lane >> 2;          // candidate slot 0..15
  const int q = lane & 3;           // element quarter
#pragma unroll
  for (int i = 0; i < 4; i++) {
    const int c = wv*4 + i;
    const size_t rid = ((size_t)b*C + c)*H + h;
    const int k = cand[rid * NC + j];
    const float* er = emb + ((size_t)k << 8);
    double a0 = 0.0, a1 = 0.0, a2 = 0.0, a3 = 0.0;
#pragma unroll
    for (int it = 0; it < 16; it++) {
      const int e0 = it*16 + q*4;
      const float4 ev = *(const float4*)(er + e0);
      a0 = fma((double)ev.x, ze[c][e0+0], a0);
      a1 = fma((double)ev.y, ze[c][e0+1], a1);
      a2 = fma((double)ev.z, ze[c][e0+2], a2);
      a3 = fma((double)ev.w, ze[c][e0+3], a3);
    }
    double dot = (a0 + a1) + (a2 + a3);
    dot += __shfl_xor(dot, 1, 64);
    dot += __shfl_xor(dot, 2, 64);
    double cv = enorm[k] - 2.0 * dot;
    int bk = k;
#pragma unroll
    for (int off = 4; off < 64; off <<= 1) {
      double ocv = __shfl_xor(cv, off, 64);
      int    okk = __shfl_xor(bk, off, 64);
      if (ocv < cv || (ocv == cv && okk < bk)) { cv = ocv; bk = okk; }
    }
    if (lane == 0) bkS[c] = bk;
  }
  __syncthreads();

  // Phase 3: z_q gather + write, decode conv + tanh
  for (int i = tid; i < C*D; i += 256) {
    int c = i >> 8, dd = i & 255;
    float v = emb[((size_t)bkS[c] << 8) + dd];
    zs[c][dd + PAD] = v;
    zq[(((size_t)b*C + c)*H + h)*D + dd] = v;
  }
  if (tid < C*2*PAD) {
    int c = tid / (2*PAD), jj = tid % (2*PAD);
    zs[c][jj < PAD ? jj : (D + PAD + (jj - PAD))] = 0.f;
  }
  __syncthreads();
  float p = 0.f;
#pragma unroll
  for (int c = 0; c < C; c++)
#pragma unroll
    for (int t = 0; t < T; t++)
      p = fmaf(wt[c*T + t], zs[c][d + t], p);
  xt[(size_t)bh * D + d] = tanhf(p);
}

// ---------------------------------------------------------------------------
extern "C" void kernel_launch(void* const* d_in, const int* in_sizes, int n_in,
                              void* d_out, int out_size, void* d_ws, size_t ws_size,
                              hipStream_t stream) {
  const float* x     = (const float*)d_in[0];
  const float* w_enc = (const float*)d_in[1];
  const float* gamma = (const float*)d_in[2];
  const float* beta  = (const float*)d_in[3];
  const float* emb   = (const float*)d_in[4];
  const float* w_dec = (const float*)d_in[5];

  float* out = (float*)d_out;
  float* xt = out;                                    // 524288
  float* zE = out + (size_t)B*H*D;                    // 8388608
  float* zq = out + (size_t)B*H*D + (size_t)B*C*H*D;  // 8388608

  char* ws = (char*)d_ws;
  double* partial = (double*)(ws);                       // 524288 B
  double* params  = (double*)(ws + 524288);              // 512 B
  double* enorm   = (double*)(ws + 524800);              // 16384 B
  float*  enormf  = (float*) (ws + 541184);              // 8192 B
  int*    cand    = (int*)   (ws + 549376);              // 32768*16*4 = 2 MiB
  __hip_bfloat16* zEb  = (__hip_bfloat16*)(ws + 2646528);   // 16 MiB
  __hip_bfloat16* embB = (__hip_bfloat16*)(ws + 19423744);  // 1 MiB

  k1_conv_stats<<<BH, 256, 0, stream>>>(x, w_enc, partial);
  k2_stats_final<<<C, 256, 0, stream>>>(partial, gamma, beta, params);
  k6_enorm<<<K, 64, 0, stream>>>(emb, enorm, enormf, embB);
  k3_ze<<<BH, 256, 0, stream>>>(x, w_enc, params, zE, zEb);
  k4_mfma<<<512, 256, 0, stream>>>(zEb, embB, enormf, cand);
  k5_fused<<<BH, 256, 0, stream>>>(x, w_enc, params, emb, enorm, cand, w_dec, zq, xt);
}

// Round 5
// 177.982 us; speedup vs baseline: 1.6441x; 1.3093x over previous
//
#include <hip/hip_runtime.h>
#include <hip/hip_bf16.h>
#include <cstddef>
#include <cstdint>

// Problem constants
#define B   32
#define C   16
#define H   64
#define D   256
#define K   2048
#define T   15
#define PAD 7
#define EPS 1e-5

#define BH      (B*H)       // 2048
#define ROWS    (B*C*H)     // 32768 VQ rows
#define N_PER_CH ((double)(B*H*D)) // 524288
#define NC  16              // candidates per row total (8 per N-half)

typedef __attribute__((ext_vector_type(8))) short bf16x8;
typedef __attribute__((ext_vector_type(4))) float f32x4;

__device__ __forceinline__ void gload_lds16(const void* g, void* l) {
  __builtin_amdgcn_global_load_lds(
      (const __attribute__((address_space(1))) unsigned int*)g,
      (__attribute__((address_space(3))) unsigned int*)l, 16, 0, 0);
}

// ---------------------------------------------------------------------------
// K1: encoder conv f64 computed ONCE. Thread = (channel c, segment s of 16 d).
// Window via 8 aligned ds_read_b128 (static reg indices). Writes raw conv
// (f32) into the zE output slot + deterministic BN partial sums.
// ---------------------------------------------------------------------------
__global__ __launch_bounds__(256) void k1_conv(
    const float* __restrict__ x, const float* __restrict__ w,
    double* __restrict__ partial /* [BH][C][2] */, float* __restrict__ zraw) {
  __shared__ __attribute__((aligned(16))) float xs[272];
  __shared__ float wsm[C*T];
  const int bh = blockIdx.x, tid = threadIdx.x;
  const int b = bh >> 6, h = bh & 63;
  const float* xrow = x + ((size_t)bh << 8);
  if (tid < C*T) wsm[tid] = w[tid];
  xs[tid] = (tid >= 7 && tid < 263) ? xrow[tid - 7] : 0.f;
  if (tid < 16) { int i = 256 + tid; xs[i] = (i < 263) ? xrow[i - 7] : 0.f; }
  __syncthreads();
  const int c = tid >> 4, s = tid & 15;
  float xr[32];
#pragma unroll
  for (int kq = 0; kq < 8; kq++)
    *(float4*)&xr[kq*4] = *(const float4*)&xs[s*16 + kq*4];
  float wv[T];
#pragma unroll
  for (int t = 0; t < T; t++) wv[t] = wsm[c*T + t];
  double sum = 0.0, sq = 0.0;
  float zf[16];
#pragma unroll
  for (int d0 = 0; d0 < 16; d0++) {
    double z = 0.0;
#pragma unroll
    for (int t = 0; t < T; t++) z = fma((double)wv[t], (double)xr[d0 + t], z);
    sum += z; sq = fma(z, z, sq);
    zf[d0] = (float)z;
  }
  float* zr = zraw + ((((size_t)b*C + c)*H + h) << 8) + s*16;
#pragma unroll
  for (int kq = 0; kq < 4; kq++)
    *(float4*)(zr + kq*4) = *(const float4*)&zf[kq*4];
#pragma unroll
  for (int off = 1; off < 16; off <<= 1) {
    sum += __shfl_xor(sum, off, 64);
    sq  += __shfl_xor(sq,  off, 64);
  }
  if (s == 0) {
    partial[(size_t)bh*(C*2) + c*2 + 0] = sum;
    partial[(size_t)bh*(C*2) + c*2 + 1] = sq;
  }
}

// ---------------------------------------------------------------------------
// K2: finalize BN per-channel params (deterministic tree)
// ---------------------------------------------------------------------------
__global__ __launch_bounds__(256) void k2_stats_final(
    const double* __restrict__ partial, const float* __restrict__ gamma,
    const float* __restrict__ beta, double* __restrict__ params) {
  __shared__ double rs[256], rq[256];
  const int c = blockIdx.x;
  const int tid = threadIdx.x;
  double s = 0.0, q = 0.0;
  for (int i = tid; i < BH; i += 256) {
    s += partial[(size_t)i * (C*2) + c*2 + 0];
    q += partial[(size_t)i * (C*2) + c*2 + 1];
  }
  rs[tid] = s; rq[tid] = q;
  __syncthreads();
  for (int off = 128; off; off >>= 1) {
    if (tid < off) { rs[tid] += rs[tid + off]; rq[tid] += rq[tid + off]; }
    __syncthreads();
  }
  if (tid == 0) {
    double m = rs[0] / N_PER_CH;
    double v = rq[0] / N_PER_CH - m * m;
    double a = (double)gamma[c] / sqrt(v + EPS);
    double b = (double)beta[c] - a * m;
    params[c*4+0] = m; params[c*4+1] = v; params[c*4+2] = a; params[c*4+3] = b;
  }
}

// ---------------------------------------------------------------------------
// K6: ||e_k||^2 in f64 (+f32 copy) + bf16 copy of emb. grid=K, 64 thr
// ---------------------------------------------------------------------------
__global__ __launch_bounds__(64) void k6_enorm(
    const float* __restrict__ emb, double* __restrict__ enorm,
    float* __restrict__ enormf, __hip_bfloat16* __restrict__ embB) {
  const int k = blockIdx.x;
  const int tid = threadIdx.x;
  const float* er = emb + (size_t)k * D;
  double s = 0.0;
  for (int i = tid; i < D; i += 64) {
    float e = er[i];
    embB[(size_t)k * D + i] = __float2bfloat16(e);
    double ed = (double)e;
    s = fma(ed, ed, s);
  }
#pragma unroll
  for (int off = 32; off; off >>= 1) s += __shfl_down(s, off, 64);
  if (tid == 0) { enorm[k] = s; enormf[k] = (float)s; }
}

// ---------------------------------------------------------------------------
// K3: elementwise affine in place on the zE slot + bf16 copy. 8 floats/thread.
// ---------------------------------------------------------------------------
__global__ __launch_bounds__(256) void k3_affine(
    float* __restrict__ zE, const double* __restrict__ params,
    __hip_bfloat16* __restrict__ zEb) {
  const size_t base = ((size_t)blockIdx.x * 256 + threadIdx.x) * 8;
  const int c = (int)((base >> 14) & 15);
  const double a = params[c*4+2], bb = params[c*4+3];
  float4 v0 = *(const float4*)(zE + base);
  float4 v1 = *(const float4*)(zE + base + 4);
  float o[8];
  o[0] = (float)fma(a, (double)v0.x, bb);
  o[1] = (float)fma(a, (double)v0.y, bb);
  o[2] = (float)fma(a, (double)v0.z, bb);
  o[3] = (float)fma(a, (double)v0.w, bb);
  o[4] = (float)fma(a, (double)v1.x, bb);
  o[5] = (float)fma(a, (double)v1.y, bb);
  o[6] = (float)fma(a, (double)v1.z, bb);
  o[7] = (float)fma(a, (double)v1.w, bb);
  *(float4*)(zE + base)     = make_float4(o[0], o[1], o[2], o[3]);
  *(float4*)(zE + base + 4) = make_float4(o[4], o[5], o[6], o[7]);
  __hip_bfloat16 hb[8];
#pragma unroll
  for (int i = 0; i < 8; i++) hb[i] = __float2bfloat16(o[i]);
  *(int4*)(zEb + base) = *(const int4*)hb;
}

// ---------------------------------------------------------------------------
// K4: MFMA phase-A, fragment-order LDS, acc double-buffer: criterion/tracker
// update of tile nt-1 spread across the 8 MFMA steps of tile nt (VALU in
// MFMA shadow). Merge LDS padded to stride 65.
// ---------------------------------------------------------------------------
__global__ __launch_bounds__(256, 2) void k4_mfma(
    const __hip_bfloat16* __restrict__ zEb, const __hip_bfloat16* __restrict__ embB,
    const float* __restrict__ enormf, int* __restrict__ cand /*[ROWS][NC]*/) {
  __shared__ __attribute__((aligned(16))) __hip_bfloat16 Ash[64][512];   // 64 KB
  __shared__ __attribute__((aligned(16))) __hip_bfloat16 Bsh[2][8][512]; // 16 KB

  const int tid  = threadIdx.x;
  const int w    = tid >> 6, lane = tid & 63;
  const int wr   = w >> 1,   wc   = w & 1;
  const int l15  = lane & 15, l4  = lane >> 4;
  const int mblk = blockIdx.x >> 1, nhalf = blockIdx.x & 1;
  const int row0 = mblk * 128;
  const int n0   = nhalf * 1024;

  // ---- prologue: A slab (64 frags) + B step 0 ----
#pragma unroll
  for (int i = 0; i < 16; i++) {
    int f = w*16 + i;
    int kk = f >> 3, mf = f & 7;
    gload_lds16(zEb + (((size_t)(row0 + mf*16 + l15)) << 8) + kk*32 + l4*8,
                &Ash[kk*8 + mf][0]);
  }
  auto stageB = [&](int t) {
    const int slot = t & 1, nt = t >> 3, kk = t & 7;
#pragma unroll
    for (int j = 0; j < 2; j++) {
      int nf = w*2 + j;
      gload_lds16(embB + (((size_t)(n0 + nt*128 + nf*16 + l15)) << 8) + kk*32 + l4*8,
                  &Bsh[slot][nf][0]);
    }
  };
  stageB(0);
  asm volatile("s_waitcnt vmcnt(0) lgkmcnt(0)" ::: "memory");
  __builtin_amdgcn_sched_barrier(0);
  __builtin_amdgcn_s_barrier();

  // trackers: 16 row-slots (m*4+r), top-2 as packed u32 keys (monotone f32 | col)
  unsigned t0[16], t1[16];
#pragma unroll
  for (int s = 0; s < 16; s++) { t0[s] = 0xFFFFFFFFu; t1[s] = 0xFFFFFFFFu; }

  f32x4 accA[4][4], accB[4][4];
  float pen1 = 0.f; int pcol = 0;

  auto runphase = [&](f32x4 (&ACC)[4][4], f32x4 (&PRV)[4][4],
                      int ntbase, int pnt, bool dp) {
#pragma unroll
    for (int m = 0; m < 4; m++)
#pragma unroll
      for (int n = 0; n < 4; n++) ACC[m][n] = (f32x4){0.f, 0.f, 0.f, 0.f};
#pragma unroll
    for (int kk = 0; kk < 8; kk++) {
      const int t = ntbase*8 + kk;
      if (t) __builtin_amdgcn_s_barrier();       // prev-step reads consumed
      if (t < 63) {
        stageB(t + 1);
        asm volatile("s_waitcnt vmcnt(2)" ::: "memory");
      } else {
        asm volatile("s_waitcnt vmcnt(0)" ::: "memory");
      }
      __builtin_amdgcn_sched_barrier(0);
      __builtin_amdgcn_s_barrier();              // stage(t) visible to all

      bf16x8 af[4], bfr[4];
#pragma unroll
      for (int m = 0; m < 4; m++)
        af[m] = *(const bf16x8*)&Ash[kk*8 + wr*4 + m][lane*8];
#pragma unroll
      for (int n = 0; n < 4; n++)
        bfr[n] = *(const bf16x8*)&Bsh[t & 1][wc*4 + n][lane*8];
#pragma unroll
      for (int m = 0; m < 4; m++)
#pragma unroll
        for (int n = 0; n < 4; n++)
          ACC[m][n] = __builtin_amdgcn_mfma_f32_16x16x32_bf16(af[m], bfr[n], ACC[m][n], 0, 0, 0);

      if (dp) {                                  // deferred epilogue slice (8 vals)
        const int n = kk >> 1, hf = kk & 1;
        if (hf == 0) {
          pcol = n0 + pnt*128 + (wc*4 + n)*16 + l15;
          pen1 = enormf[pcol];
        }
#pragma unroll
        for (int mm = 0; mm < 2; mm++) {
          const int m = hf*2 + mm;
#pragma unroll
          for (int r = 0; r < 4; r++) {
            const float cv = fmaf(-2.f, PRV[m][n][r], pen1);
            unsigned u = __float_as_uint(cv);
            unsigned key = u ^ ((unsigned)((int)u >> 31) | 0x80000000u);
            key = (key & 0xFFFFF800u) | (unsigned)pcol;
            const int s = m*4 + r;
            unsigned mx = key > t0[s] ? key : t0[s];
            t0[s] = key < t0[s] ? key : t0[s];
            t1[s] = mx < t1[s] ? mx : t1[s];
          }
        }
      }
    }
  };

  for (int nt = 0; nt < 8; nt += 2) {
    runphase(accA, accB, nt,     nt - 1, nt > 0);
    runphase(accB, accA, nt + 1, nt,     true);
  }
  // tail: process accB of nt=7
#pragma unroll
  for (int kk = 0; kk < 8; kk++) {
    const int n = kk >> 1, hf = kk & 1;
    if (hf == 0) { pcol = n0 + 7*128 + (wc*4 + n)*16 + l15; pen1 = enormf[pcol]; }
#pragma unroll
    for (int mm = 0; mm < 2; mm++) {
      const int m = hf*2 + mm;
#pragma unroll
      for (int r = 0; r < 4; r++) {
        const float cv = fmaf(-2.f, accB[m][n][r], pen1);
        unsigned u = __float_as_uint(cv);
        unsigned key = u ^ ((unsigned)((int)u >> 31) | 0x80000000u);
        key = (key & 0xFFFFF800u) | (unsigned)pcol;
        const int s = m*4 + r;
        unsigned mx = key > t0[s] ? key : t0[s];
        t0[s] = key < t0[s] ? key : t0[s];
        t1[s] = mx < t1[s] ? mx : t1[s];
      }
    }
  }

  // ---- merge 32 trackers x top-2 -> top-8 per row (stride 65: no conflicts) ----
  __syncthreads();
  unsigned* KeyM = (unsigned*)&Ash[0][0];      // [128 rows][65] = 33.3 KB
  const int tk = wc*16 + l15;
#pragma unroll
  for (int s = 0; s < 16; s++) {
    const int r = wr*64 + (s >> 2)*16 + l4*4 + (s & 3);
    KeyM[r*65 + tk*2 + 0] = t0[s];
    KeyM[r*65 + tk*2 + 1] = t1[s];
  }
  __syncthreads();
  if (tid < 128) {
    unsigned bk[8];
#pragma unroll
    for (int j = 0; j < 8; j++) bk[j] = 0xFFFFFFFFu;
    for (int e = 0; e < 64; e++) {
      unsigned v = KeyM[tid*65 + e];
      if (v < bk[7]) {
        int j = 7;
        while (j > 0 && v < bk[j-1]) { bk[j] = bk[j-1]; j--; }
        bk[j] = v;
      }
    }
    int* cr = cand + ((size_t)(row0 + tid)) * NC + nhalf*8;
#pragma unroll
    for (int j = 0; j < 8; j++) cr[j] = (int)(bk[j] & 2047u);
  }
}

// ---------------------------------------------------------------------------
// K5 (rescore + decode fused): block per (b,h).
//  Stage z_e (f32) rows to LDS; lane-parallel f64 rescore (16 cands x 4 lanes);
//  gather z_q; segmented decoder conv (5x b128 windows) + tanh.
// ---------------------------------------------------------------------------
__global__ __launch_bounds__(256) void k5_fused(
    const float* __restrict__ zE, const float* __restrict__ emb,
    const double* __restrict__ enorm, const int* __restrict__ cand,
    const float* __restrict__ wdec,
    float* __restrict__ zq, float* __restrict__ xt) {
  __shared__ __attribute__((aligned(16))) float zsh[C][256];   // 16 KB
  __shared__ __attribute__((aligned(16))) float zs[C][272];    // 17 KB
  __shared__ __attribute__((aligned(16))) float part[4][256];  // 4 KB
  __shared__ float wt[C*T];
  __shared__ int bkS[C];
  const int bh = blockIdx.x, b = bh >> 6, h = bh & 63;
  const int tid = threadIdx.x;
  const int wv = tid >> 6, lane = tid & 63;

  // stage z_e rows (16 x 1KB), linear dest = wave base + lane*16
#pragma unroll
  for (int i = 0; i < 4; i++) {
    int p = i*256 + tid;
    int c = p >> 6, cc = p & 63;
    gload_lds16(zE + ((((size_t)b*C + c)*H + h) << 8) + cc*4, &zsh[c][cc*4]);
  }
  if (tid < C*T) { int c = tid / T, t = tid % T; wt[c*T + t] = wdec[c*T + (T-1-t)]; }
  asm volatile("s_waitcnt vmcnt(0)" ::: "memory");
  __syncthreads();

  // rescore: wave wv -> channels wv*4..wv*4+3; lane = (cand j, quarter q)
  const int j = lane >> 2, q = lane & 3;
  for (int i = 0; i < 4; i++) {
    const int c = wv*4 + i;
    const size_t rid = ((size_t)b*C + c)*H + h;
    const int k = cand[rid * NC + j];
    const float* er = emb + ((size_t)k << 8);
    double a0 = 0.0, a1 = 0.0, a2 = 0.0, a3 = 0.0;
#pragma unroll
    for (int it = 0; it < 16; it++) {
      const int e0 = it*16 + q*4;
      const float4 ev = *(const float4*)(er + e0);
      const float4 zv = *(const float4*)&zsh[c][e0];
      a0 = fma((double)ev.x, (double)zv.x, a0);
      a1 = fma((double)ev.y, (double)zv.y, a1);
      a2 = fma((double)ev.z, (double)zv.z, a2);
      a3 = fma((double)ev.w, (double)zv.w, a3);
    }
    double dot = (a0 + a1) + (a2 + a3);
    dot += __shfl_xor(dot, 1, 64);
    dot += __shfl_xor(dot, 2, 64);
    double cv = enorm[k] - 2.0 * dot;
    int bk = k;
#pragma unroll
    for (int off = 4; off < 64; off <<= 1) {
      double ocv = __shfl_xor(cv, off, 64);
      int    okk = __shfl_xor(bk, off, 64);
      if (ocv < cv || (ocv == cv && okk < bk)) { cv = ocv; bk = okk; }
    }
    if (lane == 0) bkS[c] = bk;
  }
  __syncthreads();

  // gather z_q + zero pads
  for (int i2 = tid; i2 < C*D; i2 += 256) {
    int c = i2 >> 8, dd = i2 & 255;
    float v = emb[((size_t)bkS[c] << 8) + dd];
    zs[c][dd + PAD] = v;
    zq[((((size_t)b*C + c)*H + h) << 8) + dd] = v;
  }
  { int jj = tid & 15, c = tid >> 4;
    int pos = (jj < 7) ? jj : (256 + PAD + (jj - 7));   // 0..6, 263..271
    zs[c][pos] = 0.f; }
  __syncthreads();

  // decode: thread (dg = tid&63 -> 4 outputs, cg = tid>>6 -> 4 channels)
  const int dg = tid & 63, cg = tid >> 6;
  float f[20];
  float oo[4] = {0.f, 0.f, 0.f, 0.f};
#pragma unroll
  for (int ci = 0; ci < 4; ci++) {
    const int c = cg*4 + ci;
#pragma unroll
    for (int kq = 0; kq < 5; kq++)
      *(float4*)&f[kq*4] = *(const float4*)&zs[c][dg*4 + kq*4];
#pragma unroll
    for (int jj = 0; jj < 4; jj++)
#pragma unroll
      for (int t = 0; t < T; t++)
        oo[jj] = fmaf(wt[c*T + t], f[jj + t], oo[jj]);
  }
  *(float4*)&part[cg][dg*4] = make_float4(oo[0], oo[1], oo[2], oo[3]);
  __syncthreads();
  float r = part[0][tid] + part[1][tid] + part[2][tid] + part[3][tid];
  xt[((size_t)bh << 8) + tid] = tanhf(r);
}

// ---------------------------------------------------------------------------
extern "C" void kernel_launch(void* const* d_in, const int* in_sizes, int n_in,
                              void* d_out, int out_size, void* d_ws, size_t ws_size,
                              hipStream_t stream) {
  const float* x     = (const float*)d_in[0];
  const float* w_enc = (const float*)d_in[1];
  const float* gamma = (const float*)d_in[2];
  const float* beta  = (const float*)d_in[3];
  const float* emb   = (const float*)d_in[4];
  const float* w_dec = (const float*)d_in[5];

  float* out = (float*)d_out;
  float* xt = out;                                    // 524288
  float* zE = out + (size_t)B*H*D;                    // 8388608 (raw conv, then z_e)
  float* zq = out + (size_t)B*H*D + (size_t)B*C*H*D;  // 8388608

  char* ws = (char*)d_ws;
  double* partial = (double*)(ws);                       // 524288 B
  double* params  = (double*)(ws + 524288);              // 512 B
  double* enorm   = (double*)(ws + 524800);              // 16384 B
  float*  enormf  = (float*) (ws + 541184);              // 8192 B
  int*    cand    = (int*)   (ws + 549376);              // 32768*16*4 = 2 MiB
  __hip_bfloat16* zEb  = (__hip_bfloat16*)(ws + 2646528);   // 16 MiB
  __hip_bfloat16* embB = (__hip_bfloat16*)(ws + 19423744);  // 1 MiB

  k1_conv<<<BH, 256, 0, stream>>>(x, w_enc, partial, zE);
  k2_stats_final<<<C, 256, 0, stream>>>(partial, gamma, beta, params);
  k6_enorm<<<K, 64, 0, stream>>>(emb, enorm, enormf, embB);
  k3_affine<<<4096, 256, 0, stream>>>(zE, params, zEb);
  k4_mfma<<<512, 256, 0, stream>>>(zEb, embB, enormf, cand);
  k5_fused<<<BH, 256, 0, stream>>>(zE, emb, enorm, cand, w_dec, zq, xt);
}